// Round 9
// baseline (299.392 us; speedup 1.0000x reference)
//
#include <hip/hip_runtime.h>
#include <math.h>

#define B_   4
#define C_   256
#define G_   32
#define CPG  8                 // channels per group
#define N_   4096              // H*W
#define NPG  (CPG * N_)        // 32768 elements per group
#define EPS  1e-5f
#define SCALE 0.0625f          // C^-0.5 = 1/16

typedef __attribute__((ext_vector_type(8)))  __bf16 bf16x8;
typedef __attribute__((ext_vector_type(4)))  __bf16 bf16x4;
typedef __attribute__((ext_vector_type(16))) float  f32x16;

// ---------------------------------------------------------------------------
// Kernel 1a: GroupNorm partial sums. 512 blocks = 128 groups x 4 segments.
// ---------------------------------------------------------------------------
__global__ __launch_bounds__(256) void gn_stats_kernel(const float* __restrict__ x,
                                                       float* __restrict__ part) {
    int bid = blockIdx.x;
    int bg = bid >> 2, seg = bid & 3;
    const float4* xp4 = (const float4*)(x + (size_t)bg * NPG) + seg * 2048;
    int tid = threadIdx.x;

    float s = 0.f, ss = 0.f;
    for (int i = tid; i < 2048; i += 256) {
        float4 t = xp4[i];
        s  += t.x + t.y + t.z + t.w;
        ss += t.x * t.x + t.y * t.y + t.z * t.z + t.w * t.w;
    }
    #pragma unroll
    for (int off = 32; off; off >>= 1) {
        s  += __shfl_xor(s, off, 64);
        ss += __shfl_xor(ss, off, 64);
    }
    __shared__ float rs[2][4];
    int wave = tid >> 6, lane = tid & 63;
    if (lane == 0) { rs[0][wave] = s; rs[1][wave] = ss; }
    __syncthreads();
    if (tid == 0) {
        part[bid * 2]     = rs[0][0] + rs[0][1] + rs[0][2] + rs[0][3];
        part[bid * 2 + 1] = rs[1][0] + rs[1][1] + rs[1][2] + rs[1][3];
    }
}

// ---------------------------------------------------------------------------
// Kernel 1b: GroupNorm apply -> bf16 frag-interleaved (unchanged from R8).
// ---------------------------------------------------------------------------
__global__ __launch_bounds__(256) void gn_apply_kernel(const float* __restrict__ x,
                                                       const float* __restrict__ w,
                                                       const float* __restrict__ bia,
                                                       const float* __restrict__ part,
                                                       __bf16* __restrict__ xnb) {
    int bid = blockIdx.x;
    int bg = bid >> 4, seg = bid & 15;
    int b = bg >> 5, g = bg & 31;
    float s  = part[(bg * 4 + 0) * 2] + part[(bg * 4 + 1) * 2]
             + part[(bg * 4 + 2) * 2] + part[(bg * 4 + 3) * 2];
    float ss = part[(bg * 4 + 0) * 2 + 1] + part[(bg * 4 + 1) * 2 + 1]
             + part[(bg * 4 + 2) * 2 + 1] + part[(bg * 4 + 3) * 2 + 1];
    float mean = s / (float)NPG;
    float var  = ss / (float)NPG - mean * mean;
    float rstd = rsqrtf(var + EPS);

    const float* xp = x + (size_t)bg * NPG;
    int n = seg * 256 + threadIdx.x;

    bf16x8 pk;
    #pragma unroll
    for (int cc = 0; cc < 8; cc++) {
        float sc = rstd * w[g * CPG + cc];
        float sh = bia[g * CPG + cc] - mean * sc;
        pk[cc] = (__bf16)(xp[(size_t)cc * N_ + n] * sc + sh);
    }
    size_t idx = ((((size_t)(b * 128 + (n >> 5)) * 16 + (g >> 1)) * 2 + (g & 1))
                  * 32 + (n & 31)) * 8;
    *(bf16x8*)(xnb + idx) = pk;
}

// ---------------------------------------------------------------------------
// Kernel 2: QKV projection, bf16 MFMA (unchanged from R5-R8).
// ---------------------------------------------------------------------------
__global__ __launch_bounds__(256) void qkv_kernel(const __bf16* __restrict__ xnb,
                                                  const float* __restrict__ W,
                                                  const float* __restrict__ bias,
                                                  __bf16* __restrict__ q,
                                                  __bf16* __restrict__ k,
                                                  __bf16* __restrict__ v) {
    int b = blockIdx.z, ot = blockIdx.y, nc = blockIdx.x;
    int tid = threadIdx.x, wv = tid >> 6, lane = tid & 63;
    int n31 = lane & 31, q2 = lane >> 5;
    int B0 = ot * 128 + wv * 32;

    bf16x8 wf[16];
    const float* wp = W + (size_t)(B0 + n31) * C_;
    #pragma unroll
    for (int ks = 0; ks < 16; ks++) {
        float4 t0 = *(const float4*)(wp + ks * 16 + q2 * 8);
        float4 t1 = *(const float4*)(wp + ks * 16 + q2 * 8 + 4);
        bf16x8 f;
        f[0] = (__bf16)t0.x; f[1] = (__bf16)t0.y; f[2] = (__bf16)t0.z; f[3] = (__bf16)t0.w;
        f[4] = (__bf16)t1.x; f[5] = (__bf16)t1.y; f[6] = (__bf16)t1.z; f[7] = (__bf16)t1.w;
        wf[ks] = f;
    }

    float bv[16], bvv = 0.f;
    if (ot < 4) {
        #pragma unroll
        for (int gI = 0; gI < 4; gI++)
            #pragma unroll
            for (int j = 0; j < 4; j++)
                bv[gI * 4 + j] = bias[B0 + gI * 8 + 4 * q2 + j];
    } else {
        bvv = bias[B0 + n31];
    }

    const __bf16* xb = xnb + (size_t)b * 128 * 8192;

    for (int t = 0; t < 4; t++) {
        int nt = nc * 4 + t;
        const __bf16* xg = xb + (size_t)nt * 8192 + q2 * 256 + n31 * 8;
        bf16x8 xf[16];
        #pragma unroll
        for (int ks = 0; ks < 16; ks++) xf[ks] = *(const bf16x8*)(xg + ks * 512);

        f32x16 acc;
        #pragma unroll
        for (int i = 0; i < 16; i++) acc[i] = 0.f;
        if (ot < 4) {
            #pragma unroll
            for (int ks = 0; ks < 16; ks++)
                acc = __builtin_amdgcn_mfma_f32_32x32x16_bf16(wf[ks], xf[ks], acc, 0, 0, 0);
        } else {
            #pragma unroll
            for (int ks = 0; ks < 16; ks++)
                acc = __builtin_amdgcn_mfma_f32_32x32x16_bf16(xf[ks], wf[ks], acc, 0, 0, 0);
        }

        if (ot < 4) {
            int ocb = (ot < 2) ? B0 : (B0 - 256);
            __bf16* dst = (ot < 2) ? q : k;
            bool isq = (ot < 2);
            #pragma unroll
            for (int gI = 0; gI < 4; gI++) {
                bf16x4 pk;
                #pragma unroll
                for (int j = 0; j < 4; j++) {
                    float y = acc[gI * 4 + j] + bv[gI * 4 + j];
                    if (isq) y *= SCALE;
                    pk[j] = (__bf16)y;
                }
                size_t idx = ((((size_t)(b * 128 + nt) * 16 + ((ocb >> 4) + (gI >> 1))) * 2
                               + (gI & 1)) * 32 + n31) * 8 + 4 * q2;
                *(bf16x4*)(dst + idx) = pk;
            }
        } else {
            int ocb = B0 - 512;
            #pragma unroll
            for (int gI = 0; gI < 4; gI++) {
                bf16x4 pk;
                #pragma unroll
                for (int j = 0; j < 4; j++)
                    pk[j] = (__bf16)(acc[gI * 4 + j] + bvv);
                size_t idx = (((((size_t)(b * 128 + nt) * 2 + (gI >> 1)) * 2 + (gI & 1)) * 8
                               + (ocb >> 5)) * 32 + n31) * 8 + 4 * q2;
                *(bf16x4*)(v + idx) = pk;
            }
        }
    }
}

// ---------------------------------------------------------------------------
// Kernel 3: MFMA attention, 128 q-rows/block x 2-way key split -> 2 MB/CU
// global traffic (halved vs R8). 256 blocks: xcd = b*2+split (1 MB K-half +
// 1 MB V-half hot per XCD L2), qt = bid>>3 (128-row tile).
// Per 64-key chunk: K staged to dbuf LDS via global_load_lds; phase A =
// waves (rt0..3, kq0..1): S^T [32k x 32r] -> exp -> bf16 P LDS [128][68];
// phase B = wave owns 32 chans x 128 rows (4 acc tiles, V-frags hoisted).
// Partial O dumped fp32 (additive across splits); merge+normalize in proj.
// ---------------------------------------------------------------------------
#define PSTR 68   // p_lds row stride in shorts (34 words -> 2-way, free)

__global__ __launch_bounds__(512, 2) void attn_kernel(const __bf16* __restrict__ q,
                                                      const __bf16* __restrict__ k,
                                                      const __bf16* __restrict__ v,
                                                      float* __restrict__ ao0,
                                                      float* __restrict__ ao1,
                                                      float* __restrict__ l0,
                                                      float* __restrict__ l1) {
    __shared__ __bf16 k_lds[2][16384];    // 2 x 32 KB staged K chunks
    __shared__ __bf16 p_lds[128 * PSTR];  // 17.4 KB
    __shared__ float  l_lds[128];

    int bid   = blockIdx.x;
    int xcd   = bid & 7;
    int b     = xcd >> 1;
    int split = xcd & 1;
    int qt    = bid >> 3;                 // 0..31, 128-row q tile
    int n0    = qt * 128;

    int tid = threadIdx.x;
    int wid = tid >> 6, lane = tid & 63;
    int n31 = lane & 31, q2 = lane >> 5;
    int rt = wid >> 1, kq = wid & 1;      // phase-A role
    int rowA = rt * 32 + n31;             // 0..127

    if (tid < 128) l_lds[tid] = 0.f;

    // Q B-fragments for phase A (rows n0 + rt*32 .. +31): 64 VGPR, resident.
    const __bf16* qg = q + (((size_t)(b * 128 + qt * 4 + rt) * 32 + q2) * 32 + n31) * 8;
    bf16x8 qf[16];
    #pragma unroll
    for (int ks = 0; ks < 16; ks++) qf[ks] = *(const bf16x8*)(qg + ks * 512);

    const size_t BSTR = (size_t)N_ * C_;
    const __bf16* kbase = k + (size_t)b * BSTR + (size_t)split * 524288;  // keys split*2048
    const __bf16* vgb   = v + (size_t)b * BSTR + (size_t)split * 524288
                          + (size_t)q2 * 2048 + wid * 256 + n31 * 8;

    // K DMA: chunk ch = 64 keys x 256 ch = 32 KB contiguous in frag layout.
    auto dma_k = [&](int ch, int buf) {
        const __bf16* src = kbase + (size_t)ch * 16384 + wid * 2048 + lane * 8;
        __bf16* dst = &k_lds[buf][wid * 2048];
        #pragma unroll
        for (int i = 0; i < 4; i++) {
            __builtin_amdgcn_global_load_lds(
                (const __attribute__((address_space(1))) void*)(src + i * 512),
                (__attribute__((address_space(3))) void*)(dst + i * 512), 16, 0, 0);
        }
    };

    f32x16 o_acc[4];
    #pragma unroll
    for (int c = 0; c < 4; c++)
        #pragma unroll
        for (int i = 0; i < 16; i++) o_acc[c][i] = 0.f;
    float l_acc = 0.f;

    dma_k(0, 0);

    for (int ch = 0; ch < 32; ch++) {
        int cur = ch & 1;
        __syncthreads();                  // k_lds[cur] staged; p_lds free

        // ---- V prefetch: 4 frags (this wave's 32 chans x 64 keys) ---------
        bf16x8 vf[4];
        #pragma unroll
        for (int kg = 0; kg < 4; kg++)
            vf[kg] = *(const bf16x8*)(vgb + ((size_t)ch * 2 + (kg >> 1)) * 8192
                                      + (kg & 1) * 4096);

        // ---- Phase A: S^T [32 keys x 32 rows], dual chains ----------------
        const __bf16* klds = &k_lds[cur][kq * 8192];
        f32x16 s0, s1;
        #pragma unroll
        for (int i = 0; i < 16; i++) { s0[i] = 0.f; s1[i] = 0.f; }
        #pragma unroll
        for (int ks = 0; ks < 8; ks++) {
            bf16x8 ka  = *(const bf16x8*)(klds + ks * 512 + lane * 8);
            bf16x8 kb2 = *(const bf16x8*)(klds + (ks + 8) * 512 + lane * 8);
            s0 = __builtin_amdgcn_mfma_f32_32x32x16_bf16(ka,  qf[ks],     s0, 0, 0, 0);
            s1 = __builtin_amdgcn_mfma_f32_32x32x16_bf16(kb2, qf[ks + 8], s1, 0, 0, 0);
        }
        #pragma unroll
        for (int g = 0; g < 4; g++) {
            bf16x4 pw;
            #pragma unroll
            for (int j = 0; j < 4; j++) {
                float p = __expf(s0[g * 4 + j] + s1[g * 4 + j]);
                l_acc += p;
                pw[j] = (__bf16)p;
            }
            *(bf16x4*)(p_lds + rowA * PSTR + kq * 32 + 8 * g + 4 * q2) = pw;
        }
        __syncthreads();                  // P ready

        if (ch + 1 < 32) dma_k(ch + 1, cur ^ 1);   // overlaps phase B

        // ---- Phase B: O^T[32 chans (wid)][128 rows] over 64 keys ----------
        #pragma unroll
        for (int rtile = 0; rtile < 4; rtile++) {
            const __bf16* pb = p_lds + (rtile * 32 + n31) * PSTR + q2 * 8;
            #pragma unroll
            for (int kg = 0; kg < 4; kg++) {
                bf16x8 pf = *(const bf16x8*)(pb + kg * 16);
                o_acc[rtile] = __builtin_amdgcn_mfma_f32_32x32x16_bf16(vf[kg], pf, o_acc[rtile], 0, 0, 0);
            }
        }
    }

    // ---- l reduction (each phase-A lane adds its 16-key partial) ----------
    atomicAdd(&l_lds[rowA], l_acc);
    __syncthreads();

    float* aop = split ? ao1 : ao0;
    float* lp  = split ? l1  : l0;
    if (tid < 128) lp[(size_t)b * N_ + n0 + tid] = l_lds[tid];

    // fp32 partial O dump: [b][qt][wid][rtile][g][q2][n31][4] — coalesced.
    #pragma unroll
    for (int rtile = 0; rtile < 4; rtile++)
        #pragma unroll
        for (int g = 0; g < 4; g++) {
            float4 st;
            st.x = o_acc[rtile][g * 4 + 0];
            st.y = o_acc[rtile][g * 4 + 1];
            st.z = o_acc[rtile][g * 4 + 2];
            st.w = o_acc[rtile][g * 4 + 3];
            size_t idx = ((((((size_t)(b * 32 + qt) * 8 + wid) * 4 + rtile) * 4 + g)
                           * 2 + q2) * 32 + n31) * 4;
            *(float4*)(aop + idx) = st;
        }
}

// ---------------------------------------------------------------------------
// Kernel 4: out projection. Merges the two split partials, normalizes by
// l0+l1 while building B-frags, then bf16 MFMA + bias + residual -> fp32.
// ---------------------------------------------------------------------------
__global__ __launch_bounds__(256) void proj_kernel(const float* __restrict__ ao0,
                                                   const float* __restrict__ ao1,
                                                   const float* __restrict__ l0p,
                                                   const float* __restrict__ l1p,
                                                   const float* __restrict__ W2,
                                                   const float* __restrict__ bias,
                                                   const float* __restrict__ x,
                                                   float* __restrict__ out) {
    int b = blockIdx.z, ot = blockIdx.y, nc = blockIdx.x;
    int tid = threadIdx.x, wv = tid >> 6, lane = tid & 63;
    int n31 = lane & 31, q2 = lane >> 5;
    int B0 = ot * 128 + wv * 32;

    bf16x8 wf[16];
    const float* wp = W2 + (size_t)(B0 + n31) * C_;
    #pragma unroll
    for (int ks = 0; ks < 16; ks++) {
        float4 t0 = *(const float4*)(wp + ks * 16 + q2 * 8);
        float4 t1 = *(const float4*)(wp + ks * 16 + q2 * 8 + 4);
        bf16x8 f;
        f[0] = (__bf16)t0.x; f[1] = (__bf16)t0.y; f[2] = (__bf16)t0.z; f[3] = (__bf16)t0.w;
        f[4] = (__bf16)t1.x; f[5] = (__bf16)t1.y; f[6] = (__bf16)t1.z; f[7] = (__bf16)t1.w;
        wf[ks] = f;
    }
    float bv[16];
    #pragma unroll
    for (int r = 0; r < 16; r++) bv[r] = bias[B0 + (r & 3) + 8 * (r >> 2) + 4 * q2];

    for (int t = 0; t < 4; t++) {
        int nt = nc * 4 + t;                  // 32-row tile, 0..127
        int qt = nt >> 2, rtile = nt & 3;
        int n = nt * 32 + n31;
        float inv = 1.0f / (l0p[(size_t)b * N_ + n] + l1p[(size_t)b * N_ + n]);

        bf16x8 xf[16];
        #pragma unroll
        for (int ks = 0; ks < 16; ks++) {
            int oct = ks * 2 + q2;
            int wa = oct >> 2, ga = oct & 3;
            size_t base = ((((((size_t)(b * 32 + qt) * 8 + wa) * 4 + rtile) * 4 + ga)
                            * 2) * 32 + n31) * 4;
            float4 a0 = *(const float4*)(ao0 + base);
            float4 b0 = *(const float4*)(ao0 + base + 128);
            float4 a1 = *(const float4*)(ao1 + base);
            float4 b1 = *(const float4*)(ao1 + base + 128);
            bf16x8 f;
            f[0] = (__bf16)((a0.x + a1.x) * inv);
            f[1] = (__bf16)((a0.y + a1.y) * inv);
            f[2] = (__bf16)((a0.z + a1.z) * inv);
            f[3] = (__bf16)((a0.w + a1.w) * inv);
            f[4] = (__bf16)((b0.x + b1.x) * inv);
            f[5] = (__bf16)((b0.y + b1.y) * inv);
            f[6] = (__bf16)((b0.z + b1.z) * inv);
            f[7] = (__bf16)((b0.w + b1.w) * inv);
            xf[ks] = f;
        }

        f32x16 acc;
        #pragma unroll
        for (int i = 0; i < 16; i++) acc[i] = 0.f;
        #pragma unroll
        for (int ks = 0; ks < 16; ks++)
            acc = __builtin_amdgcn_mfma_f32_32x32x16_bf16(wf[ks], xf[ks], acc, 0, 0, 0);

        #pragma unroll
        for (int r = 0; r < 16; r++) {
            int o = B0 + (r & 3) + 8 * (r >> 2) + 4 * q2;
            size_t idx = ((size_t)(b * C_ + o)) * N_ + nt * 32 + n31;
            out[idx] = acc[r] + bv[r] + x[idx];
        }
    }
}

// ---------------------------------------------------------------------------
extern "C" void kernel_launch(void* const* d_in, const int* in_sizes, int n_in,
                              void* d_out, int out_size, void* d_ws, size_t ws_size,
                              hipStream_t stream) {
    const float* x     = (const float*)d_in[0];
    const float* gn_w  = (const float*)d_in[1];
    const float* gn_b  = (const float*)d_in[2];
    const float* qkv_w = (const float*)d_in[3];
    const float* qkv_b = (const float*)d_in[4];
    const float* out_w = (const float*)d_in[5];
    const float* out_b = (const float*)d_in[6];
    float* out = (float*)d_out;

    const size_t SZ = (size_t)B_ * C_ * N_;       // 4,194,304 elements
    char* base = (char*)d_ws;
    float*  ao0 = (float*)base;                   // 16.78 MB fp32 partial O
    float*  ao1 = (float*)(base + SZ * 4);        // 16.78 MB
    __bf16* xnb = (__bf16*)base;                  // aliases ao0 (dead by attn)
    __bf16* qb  = (__bf16*)(base + 2 * SZ * 4);   // 8.39 MB each
    __bf16* kb  = qb + SZ;
    __bf16* vb  = kb + SZ;
    float*  l0  = (float*)(base + 2 * SZ * 4 + 3 * SZ * 2);  // [B,N] fp32
    float*  l1  = l0 + B_ * N_;
    float*  part = l1 + B_ * N_;                  // [512][2] GN partials

    gn_stats_kernel<<<dim3(512), 256, 0, stream>>>(x, part);
    gn_apply_kernel<<<dim3(2048), 256, 0, stream>>>(x, gn_w, gn_b, part, xnb);
    qkv_kernel<<<dim3(32, 6, B_), 256, 0, stream>>>(xnb, qkv_w, qkv_b, qb, kb, vb);
    attn_kernel<<<dim3(256), 512, 0, stream>>>(qb, kb, vb, ao0, ao1, l0, l1);
    proj_kernel<<<dim3(32, 2, B_), 256, 0, stream>>>(ao0, ao1, l0, l1, out_w, out_b, x, out);
}

// Round 10
// 240.826 us; speedup vs baseline: 1.2432x; 1.2432x over previous
//
#include <hip/hip_runtime.h>
#include <math.h>

#define B_   4
#define C_   256
#define G_   32
#define CPG  8                 // channels per group
#define N_   4096              // H*W
#define NPG  (CPG * N_)        // 32768 elements per group
#define EPS  1e-5f
#define SCALE 0.0625f          // C^-0.5 = 1/16

typedef __attribute__((ext_vector_type(8)))  __bf16 bf16x8;
typedef __attribute__((ext_vector_type(4)))  __bf16 bf16x4;
typedef __attribute__((ext_vector_type(16))) float  f32x16;

// ---------------------------------------------------------------------------
// Kernel 1a: GroupNorm partial sums (unchanged from R9).
// ---------------------------------------------------------------------------
__global__ __launch_bounds__(256) void gn_stats_kernel(const float* __restrict__ x,
                                                       float* __restrict__ part) {
    int bid = blockIdx.x;
    int bg = bid >> 2, seg = bid & 3;
    const float4* xp4 = (const float4*)(x + (size_t)bg * NPG) + seg * 2048;
    int tid = threadIdx.x;

    float s = 0.f, ss = 0.f;
    for (int i = tid; i < 2048; i += 256) {
        float4 t = xp4[i];
        s  += t.x + t.y + t.z + t.w;
        ss += t.x * t.x + t.y * t.y + t.z * t.z + t.w * t.w;
    }
    #pragma unroll
    for (int off = 32; off; off >>= 1) {
        s  += __shfl_xor(s, off, 64);
        ss += __shfl_xor(ss, off, 64);
    }
    __shared__ float rs[2][4];
    int wave = tid >> 6, lane = tid & 63;
    if (lane == 0) { rs[0][wave] = s; rs[1][wave] = ss; }
    __syncthreads();
    if (tid == 0) {
        part[bid * 2]     = rs[0][0] + rs[0][1] + rs[0][2] + rs[0][3];
        part[bid * 2 + 1] = rs[1][0] + rs[1][1] + rs[1][2] + rs[1][3];
    }
}

// ---------------------------------------------------------------------------
// Kernel 1b: GroupNorm apply -> bf16 frag-interleaved (unchanged from R9).
// ---------------------------------------------------------------------------
__global__ __launch_bounds__(256) void gn_apply_kernel(const float* __restrict__ x,
                                                       const float* __restrict__ w,
                                                       const float* __restrict__ bia,
                                                       const float* __restrict__ part,
                                                       __bf16* __restrict__ xnb) {
    int bid = blockIdx.x;
    int bg = bid >> 4, seg = bid & 15;
    int b = bg >> 5, g = bg & 31;
    float s  = part[(bg * 4 + 0) * 2] + part[(bg * 4 + 1) * 2]
             + part[(bg * 4 + 2) * 2] + part[(bg * 4 + 3) * 2];
    float ss = part[(bg * 4 + 0) * 2 + 1] + part[(bg * 4 + 1) * 2 + 1]
             + part[(bg * 4 + 2) * 2 + 1] + part[(bg * 4 + 3) * 2 + 1];
    float mean = s / (float)NPG;
    float var  = ss / (float)NPG - mean * mean;
    float rstd = rsqrtf(var + EPS);

    const float* xp = x + (size_t)bg * NPG;
    int n = seg * 256 + threadIdx.x;

    bf16x8 pk;
    #pragma unroll
    for (int cc = 0; cc < 8; cc++) {
        float sc = rstd * w[g * CPG + cc];
        float sh = bia[g * CPG + cc] - mean * sc;
        pk[cc] = (__bf16)(xp[(size_t)cc * N_ + n] * sc + sh);
    }
    size_t idx = ((((size_t)(b * 128 + (n >> 5)) * 16 + (g >> 1)) * 2 + (g & 1))
                  * 32 + (n & 31)) * 8;
    *(bf16x8*)(xnb + idx) = pk;
}

// ---------------------------------------------------------------------------
// Kernel 2: QKV projection, bf16 MFMA (unchanged from R5-R9).
// ---------------------------------------------------------------------------
__global__ __launch_bounds__(256) void qkv_kernel(const __bf16* __restrict__ xnb,
                                                  const float* __restrict__ W,
                                                  const float* __restrict__ bias,
                                                  __bf16* __restrict__ q,
                                                  __bf16* __restrict__ k,
                                                  __bf16* __restrict__ v) {
    int b = blockIdx.z, ot = blockIdx.y, nc = blockIdx.x;
    int tid = threadIdx.x, wv = tid >> 6, lane = tid & 63;
    int n31 = lane & 31, q2 = lane >> 5;
    int B0 = ot * 128 + wv * 32;

    bf16x8 wf[16];
    const float* wp = W + (size_t)(B0 + n31) * C_;
    #pragma unroll
    for (int ks = 0; ks < 16; ks++) {
        float4 t0 = *(const float4*)(wp + ks * 16 + q2 * 8);
        float4 t1 = *(const float4*)(wp + ks * 16 + q2 * 8 + 4);
        bf16x8 f;
        f[0] = (__bf16)t0.x; f[1] = (__bf16)t0.y; f[2] = (__bf16)t0.z; f[3] = (__bf16)t0.w;
        f[4] = (__bf16)t1.x; f[5] = (__bf16)t1.y; f[6] = (__bf16)t1.z; f[7] = (__bf16)t1.w;
        wf[ks] = f;
    }

    float bv[16], bvv = 0.f;
    if (ot < 4) {
        #pragma unroll
        for (int gI = 0; gI < 4; gI++)
            #pragma unroll
            for (int j = 0; j < 4; j++)
                bv[gI * 4 + j] = bias[B0 + gI * 8 + 4 * q2 + j];
    } else {
        bvv = bias[B0 + n31];
    }

    const __bf16* xb = xnb + (size_t)b * 128 * 8192;

    for (int t = 0; t < 4; t++) {
        int nt = nc * 4 + t;
        const __bf16* xg = xb + (size_t)nt * 8192 + q2 * 256 + n31 * 8;
        bf16x8 xf[16];
        #pragma unroll
        for (int ks = 0; ks < 16; ks++) xf[ks] = *(const bf16x8*)(xg + ks * 512);

        f32x16 acc;
        #pragma unroll
        for (int i = 0; i < 16; i++) acc[i] = 0.f;
        if (ot < 4) {
            #pragma unroll
            for (int ks = 0; ks < 16; ks++)
                acc = __builtin_amdgcn_mfma_f32_32x32x16_bf16(wf[ks], xf[ks], acc, 0, 0, 0);
        } else {
            #pragma unroll
            for (int ks = 0; ks < 16; ks++)
                acc = __builtin_amdgcn_mfma_f32_32x32x16_bf16(xf[ks], wf[ks], acc, 0, 0, 0);
        }

        if (ot < 4) {
            int ocb = (ot < 2) ? B0 : (B0 - 256);
            __bf16* dst = (ot < 2) ? q : k;
            bool isq = (ot < 2);
            #pragma unroll
            for (int gI = 0; gI < 4; gI++) {
                bf16x4 pk;
                #pragma unroll
                for (int j = 0; j < 4; j++) {
                    float y = acc[gI * 4 + j] + bv[gI * 4 + j];
                    if (isq) y *= SCALE;
                    pk[j] = (__bf16)y;
                }
                size_t idx = ((((size_t)(b * 128 + nt) * 16 + ((ocb >> 4) + (gI >> 1))) * 2
                               + (gI & 1)) * 32 + n31) * 8 + 4 * q2;
                *(bf16x4*)(dst + idx) = pk;
            }
        } else {
            int ocb = B0 - 512;
            #pragma unroll
            for (int gI = 0; gI < 4; gI++) {
                bf16x4 pk;
                #pragma unroll
                for (int j = 0; j < 4; j++)
                    pk[j] = (__bf16)(acc[gI * 4 + j] + bvv);
                size_t idx = (((((size_t)(b * 128 + nt) * 2 + (gI >> 1)) * 2 + (gI & 1)) * 8
                               + (ocb >> 5)) * 32 + n31) * 8 + 4 * q2;
                *(bf16x4*)(v + idx) = pk;
            }
        }
    }
}

// ---------------------------------------------------------------------------
// Kernel 3: MFMA attention, PRODUCER/CONSUMER wave specialization.
// 256 blocks (1/CU): xcd = b*2+split, qt = bid>>3 (128 q-rows), 2048 keys.
// Chunks of 64 keys, 32 chunks, ONE barrier per chunk.
//  Producers (waves 0-3; kt = key-slice 32, rh = row-half 64): read staged K
//    from LDS, S^T = K*Q^T (two row-tiles share each K-frag), exp -> bf16 P
//    into ping-pong LDS buffer. No o_acc -> registers free for load batching.
//  Consumers (waves 4-7; 64 chans each): one chunk behind, read P (b128) +
//    V (global, L2), 32 MFMA into o_acc[2][4]; also issue K-DMA for ch+1
//    (V loads issued first so MFMA waits vmcnt(8), not a DMA drain).
// Per SIMD: 1 producer + 1 consumer -> MFMA/exp of one covers load stalls of
// the other. Partial O dumped fp32 (additive over split); merge in proj.
// ---------------------------------------------------------------------------
#define PSTR 68   // p_lds row stride in shorts (34 words, 2-way = free; R9-proven)

__global__ __launch_bounds__(512, 2) void attn_kernel(const __bf16* __restrict__ q,
                                                      const __bf16* __restrict__ k,
                                                      const __bf16* __restrict__ v,
                                                      float* __restrict__ ao0,
                                                      float* __restrict__ ao1,
                                                      float* __restrict__ l0,
                                                      float* __restrict__ l1) {
    __shared__ __bf16 k_lds[2][16384];     // 2 x 32 KB staged K chunks
    __shared__ __bf16 p_lds[2][128 * PSTR];// 2 x 17.4 KB ping-pong P
    __shared__ float  l_lds[128];

    int bid   = blockIdx.x;
    int xcd   = bid & 7;
    int b     = xcd >> 1;
    int split = xcd & 1;
    int qt    = bid >> 3;                  // 0..31
    int n0    = qt * 128;

    int tid = threadIdx.x;
    int wid = tid >> 6, lane = tid & 63;
    int n31 = lane & 31, q2 = lane >> 5;

    if (tid < 128) l_lds[tid] = 0.f;

    const size_t BSTR = (size_t)N_ * C_;
    const __bf16* kbase = k + (size_t)b * BSTR + (size_t)split * 524288;
    const __bf16* vbase = v + (size_t)b * BSTR + (size_t)split * 524288
                          + (size_t)q2 * 2048 + n31 * 8;

    if (wid < 4) {
        // ================= PRODUCER =================
        int kt = wid & 1;                  // 32-key slice within chunk
        int rh = wid >> 1;                 // row half: row-tiles 2rh, 2rh+1
        bf16x8 qfA[16], qfB[16];           // Q B-frags, 128 VGPR resident
        const __bf16* qgA = q + (((size_t)(b * 128 + qt * 4 + 2 * rh) * 32 + q2) * 32 + n31) * 8;
        #pragma unroll
        for (int ks = 0; ks < 16; ks++) {
            qfA[ks] = *(const bf16x8*)(qgA + ks * 512);
            qfB[ks] = *(const bf16x8*)(qgA + 8192 + ks * 512);
        }
        float lA = 0.f, lB = 0.f;

        for (int ch = 0; ch < 32; ch++) {
            __syncthreads();
            const __bf16* klds = &k_lds[ch & 1][kt * 8192];
            __bf16* pbuf = p_lds[ch & 1];

            f32x16 sA, sB;
            #pragma unroll
            for (int i = 0; i < 16; i++) { sA[i] = 0.f; sB[i] = 0.f; }
            #pragma unroll
            for (int ks = 0; ks < 16; ks++) {
                bf16x8 kf = *(const bf16x8*)(klds + ks * 512 + lane * 8);
                sA = __builtin_amdgcn_mfma_f32_32x32x16_bf16(kf, qfA[ks], sA, 0, 0, 0);
                sB = __builtin_amdgcn_mfma_f32_32x32x16_bf16(kf, qfB[ks], sB, 0, 0, 0);
            }
            #pragma unroll
            for (int g = 0; g < 4; g++) {
                bf16x4 pwA, pwB;
                #pragma unroll
                for (int j = 0; j < 4; j++) {
                    float pa = __expf(sA[g * 4 + j]);
                    float pb = __expf(sB[g * 4 + j]);
                    lA += pa; lB += pb;
                    pwA[j] = (__bf16)pa; pwB[j] = (__bf16)pb;
                }
                *(bf16x4*)(pbuf + ((2 * rh) * 32 + n31) * PSTR + kt * 32 + 8 * g + 4 * q2) = pwA;
                *(bf16x4*)(pbuf + ((2 * rh + 1) * 32 + n31) * PSTR + kt * 32 + 8 * g + 4 * q2) = pwB;
            }
        }
        atomicAdd(&l_lds[rh * 64 + n31], lA);
        atomicAdd(&l_lds[rh * 64 + 32 + n31], lB);
        __syncthreads();
        if (tid < 128) {
            float* lp = split ? l1 : l0;
            lp[(size_t)b * N_ + n0 + tid] = l_lds[tid];
        }
    } else {
        // ================= CONSUMER =================
        int cw = wid - 4;                  // owns chans [cw*64, +64)
        f32x16 o_acc[2][4];                // [ct][rt], 128 AGPR
        #pragma unroll
        for (int ct = 0; ct < 2; ct++)
            #pragma unroll
            for (int rt = 0; rt < 4; rt++)
                #pragma unroll
                for (int i = 0; i < 16; i++) o_acc[ct][rt][i] = 0.f;

        {   // DMA chunk 0 -> buf 0 (this wave's quarter: 8 KB)
            const __bf16* src = kbase + cw * 4096 + lane * 8;
            __bf16* dst = &k_lds[0][cw * 4096];
            #pragma unroll
            for (int i = 0; i < 8; i++)
                __builtin_amdgcn_global_load_lds(
                    (const __attribute__((address_space(1))) void*)(src + i * 512),
                    (__attribute__((address_space(3))) void*)(dst + i * 512), 16, 0, 0);
        }

        for (int ch = 0; ch < 32; ch++) {
            __syncthreads();
            // V loads FIRST (for chunk ch-1), so MFMA waits don't drain DMA.
            bf16x8 vf[4][2];
            if (ch > 0) {
                #pragma unroll
                for (int ks4 = 0; ks4 < 4; ks4++)
                    #pragma unroll
                    for (int ct = 0; ct < 2; ct++) {
                        size_t off = (size_t)((ch - 1) * 2 + (ks4 >> 1)) * 8192
                                   + (size_t)(ks4 & 1) * 4096 + (cw * 2 + ct) * 256;
                        vf[ks4][ct] = *(const bf16x8*)(vbase + off);
                    }
            }
            if (ch + 1 < 32) {             // DMA chunk ch+1 -> other buffer
                const __bf16* src = kbase + (size_t)(ch + 1) * 16384 + cw * 4096 + lane * 8;
                __bf16* dst = &k_lds[(ch + 1) & 1][cw * 4096];
                #pragma unroll
                for (int i = 0; i < 8; i++)
                    __builtin_amdgcn_global_load_lds(
                        (const __attribute__((address_space(1))) void*)(src + i * 512),
                        (__attribute__((address_space(3))) void*)(dst + i * 512), 16, 0, 0);
            }
            if (ch > 0) {                  // consume chunk ch-1
                const __bf16* pbuf = p_lds[(ch - 1) & 1];
                #pragma unroll
                for (int rt = 0; rt < 4; rt++) {
                    const __bf16* pb = pbuf + (rt * 32 + n31) * PSTR + q2 * 8;
                    #pragma unroll
                    for (int ks4 = 0; ks4 < 4; ks4++) {
                        bf16x8 pf = *(const bf16x8*)(pb + ks4 * 16);
                        o_acc[0][rt] = __builtin_amdgcn_mfma_f32_32x32x16_bf16(vf[ks4][0], pf, o_acc[0][rt], 0, 0, 0);
                        o_acc[1][rt] = __builtin_amdgcn_mfma_f32_32x32x16_bf16(vf[ks4][1], pf, o_acc[1][rt], 0, 0, 0);
                    }
                }
            }
        }
        __syncthreads();
        {   // tail: consume chunk 31 from p_lds[1]
            bf16x8 vf[4][2];
            #pragma unroll
            for (int ks4 = 0; ks4 < 4; ks4++)
                #pragma unroll
                for (int ct = 0; ct < 2; ct++) {
                    size_t off = (size_t)(31 * 2 + (ks4 >> 1)) * 8192
                               + (size_t)(ks4 & 1) * 4096 + (cw * 2 + ct) * 256;
                    vf[ks4][ct] = *(const bf16x8*)(vbase + off);
                }
            const __bf16* pbuf = p_lds[1];
            #pragma unroll
            for (int rt = 0; rt < 4; rt++) {
                const __bf16* pb = pbuf + (rt * 32 + n31) * PSTR + q2 * 8;
                #pragma unroll
                for (int ks4 = 0; ks4 < 4; ks4++) {
                    bf16x8 pf = *(const bf16x8*)(pb + ks4 * 16);
                    o_acc[0][rt] = __builtin_amdgcn_mfma_f32_32x32x16_bf16(vf[ks4][0], pf, o_acc[0][rt], 0, 0, 0);
                    o_acc[1][rt] = __builtin_amdgcn_mfma_f32_32x32x16_bf16(vf[ks4][1], pf, o_acc[1][rt], 0, 0, 0);
                }
            }
        }
        // fp32 partial O dump: [b][qt][cw][ct][rt][g][q2][n31][4] — coalesced.
        float* aop = split ? ao1 : ao0;
        #pragma unroll
        for (int ct = 0; ct < 2; ct++)
            #pragma unroll
            for (int rt = 0; rt < 4; rt++)
                #pragma unroll
                for (int g = 0; g < 4; g++) {
                    float4 st;
                    st.x = o_acc[ct][rt][g * 4 + 0];
                    st.y = o_acc[ct][rt][g * 4 + 1];
                    st.z = o_acc[ct][rt][g * 4 + 2];
                    st.w = o_acc[ct][rt][g * 4 + 3];
                    size_t idx = ((((((size_t)(b * 32 + qt) * 4 + cw) * 2 + ct) * 4 + rt)
                                   * 4 + g) * 2 + q2) * 128 + n31 * 4;
                    *(float4*)(aop + idx) = st;
                }
    }
}

// ---------------------------------------------------------------------------
// Kernel 4: out projection. Merges split partials (new [cw][ct] decode),
// normalizes by l0+l1 while building B-frags, bf16 MFMA + bias + residual.
// ---------------------------------------------------------------------------
__global__ __launch_bounds__(256) void proj_kernel(const float* __restrict__ ao0,
                                                   const float* __restrict__ ao1,
                                                   const float* __restrict__ l0p,
                                                   const float* __restrict__ l1p,
                                                   const float* __restrict__ W2,
                                                   const float* __restrict__ bias,
                                                   const float* __restrict__ x,
                                                   float* __restrict__ out) {
    int b = blockIdx.z, ot = blockIdx.y, nc = blockIdx.x;
    int tid = threadIdx.x, wv = tid >> 6, lane = tid & 63;
    int n31 = lane & 31, q2 = lane >> 5;
    int B0 = ot * 128 + wv * 32;

    bf16x8 wf[16];
    const float* wp = W2 + (size_t)(B0 + n31) * C_;
    #pragma unroll
    for (int ks = 0; ks < 16; ks++) {
        float4 t0 = *(const float4*)(wp + ks * 16 + q2 * 8);
        float4 t1 = *(const float4*)(wp + ks * 16 + q2 * 8 + 4);
        bf16x8 f;
        f[0] = (__bf16)t0.x; f[1] = (__bf16)t0.y; f[2] = (__bf16)t0.z; f[3] = (__bf16)t0.w;
        f[4] = (__bf16)t1.x; f[5] = (__bf16)t1.y; f[6] = (__bf16)t1.z; f[7] = (__bf16)t1.w;
        wf[ks] = f;
    }
    float bv[16];
    #pragma unroll
    for (int r = 0; r < 16; r++) bv[r] = bias[B0 + (r & 3) + 8 * (r >> 2) + 4 * q2];

    for (int t = 0; t < 4; t++) {
        int nt = nc * 4 + t;                  // 32-row tile, 0..127
        int qt = nt >> 2, rtile = nt & 3;
        int n = nt * 32 + n31;
        float inv = 1.0f / (l0p[(size_t)b * N_ + n] + l1p[(size_t)b * N_ + n]);

        bf16x8 xf[16];
        #pragma unroll
        for (int ks = 0; ks < 16; ks++) {
            int oct = ks * 2 + q2;            // chan octet 0..31
            int cw = oct >> 3, ct = (oct >> 2) & 1, ga = oct & 3;
            size_t base = ((((((size_t)(b * 32 + qt) * 4 + cw) * 2 + ct) * 4 + rtile)
                            * 4 + ga) * 2) * 128 + n31 * 4;
            float4 a0 = *(const float4*)(ao0 + base);
            float4 b0 = *(const float4*)(ao0 + base + 128);
            float4 a1 = *(const float4*)(ao1 + base);
            float4 b1 = *(const float4*)(ao1 + base + 128);
            bf16x8 f;
            f[0] = (__bf16)((a0.x + a1.x) * inv);
            f[1] = (__bf16)((a0.y + a1.y) * inv);
            f[2] = (__bf16)((a0.z + a1.z) * inv);
            f[3] = (__bf16)((a0.w + a1.w) * inv);
            f[4] = (__bf16)((b0.x + b1.x) * inv);
            f[5] = (__bf16)((b0.y + b1.y) * inv);
            f[6] = (__bf16)((b0.z + b1.z) * inv);
            f[7] = (__bf16)((b0.w + b1.w) * inv);
            xf[ks] = f;
        }

        f32x16 acc;
        #pragma unroll
        for (int i = 0; i < 16; i++) acc[i] = 0.f;
        #pragma unroll
        for (int ks = 0; ks < 16; ks++)
            acc = __builtin_amdgcn_mfma_f32_32x32x16_bf16(wf[ks], xf[ks], acc, 0, 0, 0);

        #pragma unroll
        for (int r = 0; r < 16; r++) {
            int o = B0 + (r & 3) + 8 * (r >> 2) + 4 * q2;
            size_t idx = ((size_t)(b * C_ + o)) * N_ + nt * 32 + n31;
            out[idx] = acc[r] + bv[r] + x[idx];
        }
    }
}

// ---------------------------------------------------------------------------
extern "C" void kernel_launch(void* const* d_in, const int* in_sizes, int n_in,
                              void* d_out, int out_size, void* d_ws, size_t ws_size,
                              hipStream_t stream) {
    const float* x     = (const float*)d_in[0];
    const float* gn_w  = (const float*)d_in[1];
    const float* gn_b  = (const float*)d_in[2];
    const float* qkv_w = (const float*)d_in[3];
    const float* qkv_b = (const float*)d_in[4];
    const float* out_w = (const float*)d_in[5];
    const float* out_b = (const float*)d_in[6];
    float* out = (float*)d_out;

    const size_t SZ = (size_t)B_ * C_ * N_;       // 4,194,304 elements
    char* base = (char*)d_ws;
    float*  ao0 = (float*)base;                   // 16.78 MB fp32 partial O
    float*  ao1 = (float*)(base + SZ * 4);        // 16.78 MB
    __bf16* xnb = (__bf16*)base;                  // aliases ao0 (dead by attn)
    __bf16* qb  = (__bf16*)(base + 2 * SZ * 4);   // 8.39 MB each
    __bf16* kb  = qb + SZ;
    __bf16* vb  = kb + SZ;
    float*  l0  = (float*)(base + 2 * SZ * 4 + 3 * SZ * 2);  // [B,N] fp32
    float*  l1  = l0 + B_ * N_;
    float*  part = l1 + B_ * N_;                  // [512][2] GN partials

    gn_stats_kernel<<<dim3(512), 256, 0, stream>>>(x, part);
    gn_apply_kernel<<<dim3(2048), 256, 0, stream>>>(x, gn_w, gn_b, part, xnb);
    qkv_kernel<<<dim3(32, 6, B_), 256, 0, stream>>>(xnb, qkv_w, qkv_b, qb, kb, vb);
    attn_kernel<<<dim3(256), 512, 0, stream>>>(qb, kb, vb, ao0, ao1, l0, l1);
    proj_kernel<<<dim3(32, 2, B_), 256, 0, stream>>>(ao0, ao1, l0, l1, out_w, out_b, x, out);
}

// Round 11
// 229.715 us; speedup vs baseline: 1.3033x; 1.0484x over previous
//
#include <hip/hip_runtime.h>
#include <math.h>

#define B_   4
#define C_   256
#define G_   32
#define CPG  8                 // channels per group
#define N_   4096              // H*W
#define NPG  (CPG * N_)        // 32768 elements per group
#define EPS  1e-5f
#define SCALE 0.0625f          // C^-0.5 = 1/16

typedef __attribute__((ext_vector_type(8)))  __bf16 bf16x8;
typedef __attribute__((ext_vector_type(4)))  __bf16 bf16x4;
typedef __attribute__((ext_vector_type(16))) float  f32x16;

// ---------------------------------------------------------------------------
// Kernel 1a: GroupNorm partial sums (unchanged from R9/R10).
// ---------------------------------------------------------------------------
__global__ __launch_bounds__(256) void gn_stats_kernel(const float* __restrict__ x,
                                                       float* __restrict__ part) {
    int bid = blockIdx.x;
    int bg = bid >> 2, seg = bid & 3;
    const float4* xp4 = (const float4*)(x + (size_t)bg * NPG) + seg * 2048;
    int tid = threadIdx.x;

    float s = 0.f, ss = 0.f;
    for (int i = tid; i < 2048; i += 256) {
        float4 t = xp4[i];
        s  += t.x + t.y + t.z + t.w;
        ss += t.x * t.x + t.y * t.y + t.z * t.z + t.w * t.w;
    }
    #pragma unroll
    for (int off = 32; off; off >>= 1) {
        s  += __shfl_xor(s, off, 64);
        ss += __shfl_xor(ss, off, 64);
    }
    __shared__ float rs[2][4];
    int wave = tid >> 6, lane = tid & 63;
    if (lane == 0) { rs[0][wave] = s; rs[1][wave] = ss; }
    __syncthreads();
    if (tid == 0) {
        part[bid * 2]     = rs[0][0] + rs[0][1] + rs[0][2] + rs[0][3];
        part[bid * 2 + 1] = rs[1][0] + rs[1][1] + rs[1][2] + rs[1][3];
    }
}

// ---------------------------------------------------------------------------
// Kernel 1b: GroupNorm apply -> bf16 frag-interleaved (unchanged).
// ---------------------------------------------------------------------------
__global__ __launch_bounds__(256) void gn_apply_kernel(const float* __restrict__ x,
                                                       const float* __restrict__ w,
                                                       const float* __restrict__ bia,
                                                       const float* __restrict__ part,
                                                       __bf16* __restrict__ xnb) {
    int bid = blockIdx.x;
    int bg = bid >> 4, seg = bid & 15;
    int b = bg >> 5, g = bg & 31;
    float s  = part[(bg * 4 + 0) * 2] + part[(bg * 4 + 1) * 2]
             + part[(bg * 4 + 2) * 2] + part[(bg * 4 + 3) * 2];
    float ss = part[(bg * 4 + 0) * 2 + 1] + part[(bg * 4 + 1) * 2 + 1]
             + part[(bg * 4 + 2) * 2 + 1] + part[(bg * 4 + 3) * 2 + 1];
    float mean = s / (float)NPG;
    float var  = ss / (float)NPG - mean * mean;
    float rstd = rsqrtf(var + EPS);

    const float* xp = x + (size_t)bg * NPG;
    int n = seg * 256 + threadIdx.x;

    bf16x8 pk;
    #pragma unroll
    for (int cc = 0; cc < 8; cc++) {
        float sc = rstd * w[g * CPG + cc];
        float sh = bia[g * CPG + cc] - mean * sc;
        pk[cc] = (__bf16)(xp[(size_t)cc * N_ + n] * sc + sh);
    }
    size_t idx = ((((size_t)(b * 128 + (n >> 5)) * 16 + (g >> 1)) * 2 + (g & 1))
                  * 32 + (n & 31)) * 8;
    *(bf16x8*)(xnb + idx) = pk;
}

// ---------------------------------------------------------------------------
// Kernel 2: QKV projection, bf16 MFMA (unchanged from R5-R10).
// ---------------------------------------------------------------------------
__global__ __launch_bounds__(256) void qkv_kernel(const __bf16* __restrict__ xnb,
                                                  const float* __restrict__ W,
                                                  const float* __restrict__ bias,
                                                  __bf16* __restrict__ q,
                                                  __bf16* __restrict__ k,
                                                  __bf16* __restrict__ v) {
    int b = blockIdx.z, ot = blockIdx.y, nc = blockIdx.x;
    int tid = threadIdx.x, wv = tid >> 6, lane = tid & 63;
    int n31 = lane & 31, q2 = lane >> 5;
    int B0 = ot * 128 + wv * 32;

    bf16x8 wf[16];
    const float* wp = W + (size_t)(B0 + n31) * C_;
    #pragma unroll
    for (int ks = 0; ks < 16; ks++) {
        float4 t0 = *(const float4*)(wp + ks * 16 + q2 * 8);
        float4 t1 = *(const float4*)(wp + ks * 16 + q2 * 8 + 4);
        bf16x8 f;
        f[0] = (__bf16)t0.x; f[1] = (__bf16)t0.y; f[2] = (__bf16)t0.z; f[3] = (__bf16)t0.w;
        f[4] = (__bf16)t1.x; f[5] = (__bf16)t1.y; f[6] = (__bf16)t1.z; f[7] = (__bf16)t1.w;
        wf[ks] = f;
    }

    float bv[16], bvv = 0.f;
    if (ot < 4) {
        #pragma unroll
        for (int gI = 0; gI < 4; gI++)
            #pragma unroll
            for (int j = 0; j < 4; j++)
                bv[gI * 4 + j] = bias[B0 + gI * 8 + 4 * q2 + j];
    } else {
        bvv = bias[B0 + n31];
    }

    const __bf16* xb = xnb + (size_t)b * 128 * 8192;

    for (int t = 0; t < 4; t++) {
        int nt = nc * 4 + t;
        const __bf16* xg = xb + (size_t)nt * 8192 + q2 * 256 + n31 * 8;
        bf16x8 xf[16];
        #pragma unroll
        for (int ks = 0; ks < 16; ks++) xf[ks] = *(const bf16x8*)(xg + ks * 512);

        f32x16 acc;
        #pragma unroll
        for (int i = 0; i < 16; i++) acc[i] = 0.f;
        if (ot < 4) {
            #pragma unroll
            for (int ks = 0; ks < 16; ks++)
                acc = __builtin_amdgcn_mfma_f32_32x32x16_bf16(wf[ks], xf[ks], acc, 0, 0, 0);
        } else {
            #pragma unroll
            for (int ks = 0; ks < 16; ks++)
                acc = __builtin_amdgcn_mfma_f32_32x32x16_bf16(xf[ks], wf[ks], acc, 0, 0, 0);
        }

        if (ot < 4) {
            int ocb = (ot < 2) ? B0 : (B0 - 256);
            __bf16* dst = (ot < 2) ? q : k;
            bool isq = (ot < 2);
            #pragma unroll
            for (int gI = 0; gI < 4; gI++) {
                bf16x4 pk;
                #pragma unroll
                for (int j = 0; j < 4; j++) {
                    float y = acc[gI * 4 + j] + bv[gI * 4 + j];
                    if (isq) y *= SCALE;
                    pk[j] = (__bf16)y;
                }
                size_t idx = ((((size_t)(b * 128 + nt) * 16 + ((ocb >> 4) + (gI >> 1))) * 2
                               + (gI & 1)) * 32 + n31) * 8 + 4 * q2;
                *(bf16x4*)(dst + idx) = pk;
            }
        } else {
            int ocb = B0 - 512;
            #pragma unroll
            for (int gI = 0; gI < 4; gI++) {
                bf16x4 pk;
                #pragma unroll
                for (int j = 0; j < 4; j++)
                    pk[j] = (__bf16)(acc[gI * 4 + j] + bvv);
                size_t idx = (((((size_t)(b * 128 + nt) * 2 + (gI >> 1)) * 2 + (gI & 1)) * 8
                               + (ocb >> 5)) * 32 + n31) * 8 + 4 * q2;
                *(bf16x4*)(v + idx) = pk;
            }
        }
    }
}

// ---------------------------------------------------------------------------
// Kernel 3: MFMA attention, producer/consumer with 2 BLOCKS PER CU.
// 512 blocks = 4 b x 2 split x 64 qt (64 q-rows); xcd = b*2+split.
// Chunks of 64 keys, 32 chunks. No K LDS — producers read K-frags straight
// from global (L2); LDS holds only the P ping-pong (2 x 8.5 KB) -> 2 blocks
// co-resident, 4 waves/SIMD (2P+2C from different blocks), independent
// barriers.
//  Producers (waves 0-3: kt = 32-key slice, rt = 32-row tile): 16 MFMA ->
//    S^T tile, exp -> bf16 P. qf 64 regs resident, no o_acc.
//  Consumers (waves 4-7: cw = 64-chan slice): one chunk behind; per ct-half
//    load 4 V-frags then 2x4 MFMA; o_acc[2][2] = 64 regs only.
// Partial O dumped fp32 (additive over split); merge+normalize in proj.
// ---------------------------------------------------------------------------
#define PSTR 68   // p_lds row stride in shorts (34 words, 2-way = free)

__global__ __launch_bounds__(512, 4) void attn_kernel(const __bf16* __restrict__ q,
                                                      const __bf16* __restrict__ k,
                                                      const __bf16* __restrict__ v,
                                                      float* __restrict__ ao0,
                                                      float* __restrict__ ao1,
                                                      float* __restrict__ l0,
                                                      float* __restrict__ l1) {
    __shared__ __bf16 p_lds[2][64 * PSTR];   // 2 x 8.5 KB ping-pong P
    __shared__ float  l_lds[64];

    int bid   = blockIdx.x;
    int xcd   = bid & 7;
    int b     = xcd >> 1;
    int split = xcd & 1;
    int qt    = bid >> 3;                    // 0..63, 64-row q tile
    int n0    = qt * 64;

    int tid = threadIdx.x;
    int wid = tid >> 6, lane = tid & 63;
    int n31 = lane & 31, q2 = lane >> 5;

    if (tid < 64) l_lds[tid] = 0.f;

    const size_t BSTR = (size_t)N_ * C_;

    if (wid < 4) {
        // ================= PRODUCER =================
        int kt = wid & 1;                    // 32-key slice within 64-key chunk
        int rt = wid >> 1;                   // 32-row tile within 64 rows
        const __bf16* qg = q + (size_t)(b * 128 + qt * 2 + rt) * 8192
                           + q2 * 256 + n31 * 8;
        bf16x8 qf[16];
        #pragma unroll
        for (int ks = 0; ks < 16; ks++) qf[ks] = *(const bf16x8*)(qg + ks * 512);

        const __bf16* kbase = k + (size_t)(b * 128 + split * 64 + kt) * 8192
                              + q2 * 256 + n31 * 8;
        float l_acc = 0.f;

        for (int ch = 0; ch < 32; ch++) {
            __syncthreads();
            const __bf16* kg = kbase + (size_t)ch * 16384;
            f32x16 s;
            #pragma unroll
            for (int i = 0; i < 16; i++) s[i] = 0.f;
            #pragma unroll
            for (int ks = 0; ks < 16; ks++) {
                bf16x8 kf = *(const bf16x8*)(kg + ks * 512);
                s = __builtin_amdgcn_mfma_f32_32x32x16_bf16(kf, qf[ks], s, 0, 0, 0);
            }
            __bf16* pbuf = p_lds[ch & 1];
            #pragma unroll
            for (int g = 0; g < 4; g++) {
                bf16x4 pw;
                #pragma unroll
                for (int j = 0; j < 4; j++) {
                    float p = __expf(s[g * 4 + j]);
                    l_acc += p;
                    pw[j] = (__bf16)p;
                }
                *(bf16x4*)(pbuf + (rt * 32 + n31) * PSTR + kt * 32 + 8 * g + 4 * q2) = pw;
            }
        }
        atomicAdd(&l_lds[rt * 32 + n31], l_acc);
        __syncthreads();
        if (tid < 64) {
            float* lp = split ? l1 : l0;
            lp[(size_t)b * N_ + n0 + tid] = l_lds[tid];
        }
    } else {
        // ================= CONSUMER =================
        int cw = wid - 4;                    // owns chans [cw*64, +64)
        const __bf16* vbase = v + (size_t)b * BSTR + (size_t)split * 524288
                              + (size_t)q2 * 2048 + n31 * 8;
        f32x16 o_acc[2][2];                  // [ct][rt], 64 regs
        #pragma unroll
        for (int ct = 0; ct < 2; ct++)
            #pragma unroll
            for (int rt = 0; rt < 2; rt++)
                #pragma unroll
                for (int i = 0; i < 16; i++) o_acc[ct][rt][i] = 0.f;

        for (int ch = 0; ch < 32; ch++) {
            __syncthreads();
            if (ch > 0) {
                int cc = ch - 1;
                const __bf16* pbuf = p_lds[cc & 1];
                #pragma unroll
                for (int ct = 0; ct < 2; ct++) {
                    bf16x8 vf[4];
                    #pragma unroll
                    for (int ks4 = 0; ks4 < 4; ks4++) {
                        size_t off = (size_t)(cc * 2 + (ks4 >> 1)) * 8192
                                   + (size_t)(ks4 & 1) * 4096 + (cw * 2 + ct) * 256;
                        vf[ks4] = *(const bf16x8*)(vbase + off);
                    }
                    #pragma unroll
                    for (int rt = 0; rt < 2; rt++) {
                        const __bf16* pb = pbuf + (rt * 32 + n31) * PSTR + q2 * 8;
                        #pragma unroll
                        for (int ks4 = 0; ks4 < 4; ks4++) {
                            bf16x8 pf = *(const bf16x8*)(pb + ks4 * 16);
                            o_acc[ct][rt] = __builtin_amdgcn_mfma_f32_32x32x16_bf16(
                                vf[ks4], pf, o_acc[ct][rt], 0, 0, 0);
                        }
                    }
                }
            }
        }
        __syncthreads();
        {   // tail: consume chunk 31 from p_lds[1]
            int cc = 31;
            const __bf16* pbuf = p_lds[1];
            #pragma unroll
            for (int ct = 0; ct < 2; ct++) {
                bf16x8 vf[4];
                #pragma unroll
                for (int ks4 = 0; ks4 < 4; ks4++) {
                    size_t off = (size_t)(cc * 2 + (ks4 >> 1)) * 8192
                               + (size_t)(ks4 & 1) * 4096 + (cw * 2 + ct) * 256;
                    vf[ks4] = *(const bf16x8*)(vbase + off);
                }
                #pragma unroll
                for (int rt = 0; rt < 2; rt++) {
                    const __bf16* pb = pbuf + (rt * 32 + n31) * PSTR + q2 * 8;
                    #pragma unroll
                    for (int ks4 = 0; ks4 < 4; ks4++) {
                        bf16x8 pf = *(const bf16x8*)(pb + ks4 * 16);
                        o_acc[ct][rt] = __builtin_amdgcn_mfma_f32_32x32x16_bf16(
                            vf[ks4], pf, o_acc[ct][rt], 0, 0, 0);
                    }
                }
            }
        }
        // fp32 partial O dump: [b][qt][cw][ct][rt][g][q2][n31][4] — coalesced.
        float* aop = split ? ao1 : ao0;
        #pragma unroll
        for (int ct = 0; ct < 2; ct++)
            #pragma unroll
            for (int rt = 0; rt < 2; rt++)
                #pragma unroll
                for (int g = 0; g < 4; g++) {
                    float4 st;
                    st.x = o_acc[ct][rt][g * 4 + 0];
                    st.y = o_acc[ct][rt][g * 4 + 1];
                    st.z = o_acc[ct][rt][g * 4 + 2];
                    st.w = o_acc[ct][rt][g * 4 + 3];
                    size_t idx = ((((((size_t)(b * 64 + qt) * 4 + cw) * 2 + ct) * 2 + rt)
                                   * 4 + g) * 2 + q2) * 128 + n31 * 4;
                    *(float4*)(aop + idx) = st;
                }
    }
}

// ---------------------------------------------------------------------------
// Kernel 4: out projection. Merges split partials (R11 [qt64][cw4][ct][rt]
// decode), normalizes by l0+l1 while building B-frags, bf16 MFMA + bias +
// residual -> fp32 out.
// ---------------------------------------------------------------------------
__global__ __launch_bounds__(256) void proj_kernel(const float* __restrict__ ao0,
                                                   const float* __restrict__ ao1,
                                                   const float* __restrict__ l0p,
                                                   const float* __restrict__ l1p,
                                                   const float* __restrict__ W2,
                                                   const float* __restrict__ bias,
                                                   const float* __restrict__ x,
                                                   float* __restrict__ out) {
    int b = blockIdx.z, ot = blockIdx.y, nc = blockIdx.x;
    int tid = threadIdx.x, wv = tid >> 6, lane = tid & 63;
    int n31 = lane & 31, q2 = lane >> 5;
    int B0 = ot * 128 + wv * 32;

    bf16x8 wf[16];
    const float* wp = W2 + (size_t)(B0 + n31) * C_;
    #pragma unroll
    for (int ks = 0; ks < 16; ks++) {
        float4 t0 = *(const float4*)(wp + ks * 16 + q2 * 8);
        float4 t1 = *(const float4*)(wp + ks * 16 + q2 * 8 + 4);
        bf16x8 f;
        f[0] = (__bf16)t0.x; f[1] = (__bf16)t0.y; f[2] = (__bf16)t0.z; f[3] = (__bf16)t0.w;
        f[4] = (__bf16)t1.x; f[5] = (__bf16)t1.y; f[6] = (__bf16)t1.z; f[7] = (__bf16)t1.w;
        wf[ks] = f;
    }
    float bv[16];
    #pragma unroll
    for (int r = 0; r < 16; r++) bv[r] = bias[B0 + (r & 3) + 8 * (r >> 2) + 4 * q2];

    for (int t = 0; t < 4; t++) {
        int nt = nc * 4 + t;                  // 32-row tile, 0..127
        int qt = nt >> 1, rtile = nt & 1;
        int n = nt * 32 + n31;
        float inv = 1.0f / (l0p[(size_t)b * N_ + n] + l1p[(size_t)b * N_ + n]);

        bf16x8 xf[16];
        #pragma unroll
        for (int ks = 0; ks < 16; ks++) {
            int oct = ks * 2 + q2;            // chan octet 0..31
            int cw = oct >> 3, ct = (oct >> 2) & 1, ga = oct & 3;
            size_t base = ((((((size_t)(b * 64 + qt) * 4 + cw) * 2 + ct) * 2 + rtile)
                            * 4 + ga) * 2) * 128 + n31 * 4;
            float4 a0 = *(const float4*)(ao0 + base);
            float4 b0 = *(const float4*)(ao0 + base + 128);
            float4 a1 = *(const float4*)(ao1 + base);
            float4 b1 = *(const float4*)(ao1 + base + 128);
            bf16x8 f;
            f[0] = (__bf16)((a0.x + a1.x) * inv);
            f[1] = (__bf16)((a0.y + a1.y) * inv);
            f[2] = (__bf16)((a0.z + a1.z) * inv);
            f[3] = (__bf16)((a0.w + a1.w) * inv);
            f[4] = (__bf16)((b0.x + b1.x) * inv);
            f[5] = (__bf16)((b0.y + b1.y) * inv);
            f[6] = (__bf16)((b0.z + b1.z) * inv);
            f[7] = (__bf16)((b0.w + b1.w) * inv);
            xf[ks] = f;
        }

        f32x16 acc;
        #pragma unroll
        for (int i = 0; i < 16; i++) acc[i] = 0.f;
        #pragma unroll
        for (int ks = 0; ks < 16; ks++)
            acc = __builtin_amdgcn_mfma_f32_32x32x16_bf16(wf[ks], xf[ks], acc, 0, 0, 0);

        #pragma unroll
        for (int r = 0; r < 16; r++) {
            int o = B0 + (r & 3) + 8 * (r >> 2) + 4 * q2;
            size_t idx = ((size_t)(b * C_ + o)) * N_ + nt * 32 + n31;
            out[idx] = acc[r] + bv[r] + x[idx];
        }
    }
}

// ---------------------------------------------------------------------------
extern "C" void kernel_launch(void* const* d_in, const int* in_sizes, int n_in,
                              void* d_out, int out_size, void* d_ws, size_t ws_size,
                              hipStream_t stream) {
    const float* x     = (const float*)d_in[0];
    const float* gn_w  = (const float*)d_in[1];
    const float* gn_b  = (const float*)d_in[2];
    const float* qkv_w = (const float*)d_in[3];
    const float* qkv_b = (const float*)d_in[4];
    const float* out_w = (const float*)d_in[5];
    const float* out_b = (const float*)d_in[6];
    float* out = (float*)d_out;

    const size_t SZ = (size_t)B_ * C_ * N_;       // 4,194,304 elements
    char* base = (char*)d_ws;
    float*  ao0 = (float*)base;                   // 16.78 MB fp32 partial O
    float*  ao1 = (float*)(base + SZ * 4);        // 16.78 MB
    __bf16* xnb = (__bf16*)base;                  // aliases ao0 (dead by attn)
    __bf16* qb  = (__bf16*)(base + 2 * SZ * 4);   // 8.39 MB each
    __bf16* kb  = qb + SZ;
    __bf16* vb  = kb + SZ;
    float*  l0  = (float*)(base + 2 * SZ * 4 + 3 * SZ * 2);  // [B,N] fp32
    float*  l1  = l0 + B_ * N_;
    float*  part = l1 + B_ * N_;                  // [512][2] GN partials

    gn_stats_kernel<<<dim3(512), 256, 0, stream>>>(x, part);
    gn_apply_kernel<<<dim3(2048), 256, 0, stream>>>(x, gn_w, gn_b, part, xnb);
    qkv_kernel<<<dim3(32, 6, B_), 256, 0, stream>>>(xnb, qkv_w, qkv_b, qb, kb, vb);
    attn_kernel<<<dim3(512), 512, 0, stream>>>(qb, kb, vb, ao0, ao1, l0, l1);
    proj_kernel<<<dim3(32, 2, B_), 256, 0, stream>>>(ao0, ao1, l0, l1, out_w, out_b, x, out);
}